// Round 14
// baseline (285.192 us; speedup 1.0000x reference)
//
#include <hip/hip_runtime.h>
#include <stdint.h>

typedef unsigned short ushort_t;
typedef __attribute__((ext_vector_type(8))) short bf16x8;   // 4 VGPRs, 8 bf16
typedef __attribute__((ext_vector_type(4))) float f32x4;    // MFMA C/D

#define B_   128
#define S_   50
#define D_   128
#define ALPHA_ 0.2f

__device__ __forceinline__ float bf2f(ushort_t u){
  return __uint_as_float(((uint32_t)u) << 16);
}
__device__ __forceinline__ ushort_t f2bf(float f){
  uint32_t x = __float_as_uint(f);
  x = (x + 0x7fffu + ((x >> 16) & 1u)) >> 16;
  return (ushort_t)x;
}
__device__ __forceinline__ float leaky(float x){ return x >= 0.f ? x : ALPHA_*x; }

// ---- detect: are float inputs bf16-packed (flag=1) or f32 (flag=0)? -------
__global__ void detect_kernel(const uint32_t* __restrict__ emb_raw, int* __restrict__ flag){
  if (threadIdx.x == 0 && blockIdx.x == 0){
    int ok = 1;
    for (int i = 0; i < 64; i++){
      uint32_t lo = emb_raw[i] & 0xffffu;
      uint32_t ex = (lo >> 7) & 0xFFu;
      if (!(lo == 0u || (ex >= 64u && ex <= 126u))) ok = 0;
    }
    *flag = ok;
  }
}

// ---- cvt_all: all six float tensors -> contiguous bf16 dst ----------------
__global__ void cvt_all(const void* __restrict__ p0, const void* __restrict__ p1,
                        const void* __restrict__ p2, const void* __restrict__ p3,
                        const void* __restrict__ p4, const void* __restrict__ p5,
                        ushort_t* __restrict__ dst, const int* __restrict__ flag){
  const int seg_end[6] = {6400000, 6400512, 6433280, 6433536, 6499072, 6499328};
  int base = (blockIdx.x*256 + threadIdx.x) * 4;
  if (base >= 6499328) return;
  int s = 0;
  while (base >= seg_end[s]) s++;
  int segbase = (s == 0) ? 0 : seg_end[s-1];
  const void* src = (s==0)?p0:(s==1)?p1:(s==2)?p2:(s==3)?p3:(s==4)?p4:p5;
  int off = base - segbase;
  union { ushort_t u[4]; uint2 d2; } o;
  if (*flag){
    o.d2 = *(const uint2*)((const ushort_t*)src + off);
  } else {
    float4 v = *(const float4*)((const float*)src + off);
    o.u[0] = f2bf(v.x); o.u[1] = f2bf(v.y); o.u[2] = f2bf(v.z); o.u[3] = f2bf(v.w);
  }
  *(uint2*)(dst + base) = o.d2;
}

// ---- prep_frags: pre-swizzle w1 (B-frag order) and w3 (A-frag order) ------
// w1f[h][i], i in [0,2048): kt=i>>9, t=(i>>6)&7, lane=i&63
// w3f[h][i], i in [0,4096): kt=i>>9, t=(i>>6)&7, lane=i&63
__global__ void prep_frags(const ushort_t* __restrict__ w1, const ushort_t* __restrict__ w3,
                           uint4* __restrict__ w1f, uint4* __restrict__ w3f){
  int id = blockIdx.x*256 + threadIdx.x;   // total 12288
  if (id >= 12288) return;
  if (id < 4096){
    int h = id >> 11, i = id & 2047;
    int kt = i >> 9, rem = i & 511, t = rem >> 6, ln = rem & 63;
    int q = ln >> 4, c = ln & 15;
    const ushort_t* w = w1 + h*16384;
    union { ushort_t u[8]; uint4 q4; } e;
    #pragma unroll
    for (int j = 0; j < 8; j++)
      e.u[j] = w[(32*kt + q*8 + j)*128 + 16*t + c];
    w1f[h*2048 + i] = e.q4;
  } else {
    int id2 = id - 4096;
    int h = id2 >> 12, i = id2 & 4095;
    int kt = i >> 9, rem = i & 511, t = rem >> 6, ln = rem & 63;
    int q = ln >> 4, c = ln & 15;
    const ushort_t* w = w3 + h*32768;
    union { ushort_t u[8]; uint4 q4; } e;
    #pragma unroll
    for (int j = 0; j < 8; j++)
      e.u[j] = w[(32*kt + q*8 + j)*128 + 16*t + c];
    w3f[h*4096 + i] = e.q4;
  }
}

// ---- sess: masked mean of item embeddings -> bf16 (B,D) -------------------
__global__ void sess_kernel(const int* __restrict__ item, const int* __restrict__ mask,
                            const ushort_t* __restrict__ emb, ushort_t* __restrict__ sessb){
  int b = blockIdx.x, d = threadIdx.x;
  float acc = 0.f, den = 0.f;
  for (int s = 0; s < S_; s++){
    float fm = (float)mask[b*S_ + s];
    int id = item[b*S_ + s];
    acc += fm * bf2f(emb[(size_t)id*D_ + d]);
    den += fm;
  }
  sessb[b*D_ + d] = f2bf(acc / den);
}

// ---- local attention via MFMA: one block per (b, mi) 16-row i-tile --------
__global__ __launch_bounds__(256) void local_mfma2(
    const int* __restrict__ inputs, const int* __restrict__ adj,
    const ushort_t* __restrict__ emb, const ushort_t* __restrict__ alocb,
    ushort_t* __restrict__ hlb){
  __shared__ ushort_t hS[64][136];   // h[j][d], row stride 272B
  __shared__ float    attS[16][68];  // att tile
  __shared__ int      sids[64];
  int blk = blockIdx.x;
  int b  = blk >> 2;
  int mi = blk & 3;                  // i-tile: rows mi*16 .. mi*16+15
  int tid = threadIdx.x;
  if (tid < 64) sids[tid] = (tid < S_) ? inputs[b*S_ + tid] : 0;
  __syncthreads();
  for (int idx = tid; idx < 64*16; idx += 256){   // 64 rows x 16 chunks of 8 bf16 (16B)
    int j = idx >> 4, ch = idx & 15;
    uint4 v = {0u, 0u, 0u, 0u};
    if (j < S_) v = *(const uint4*)(emb + (size_t)sids[j]*D_ + ch*8);
    *(uint4*)(&hS[j][ch*8]) = v;
  }
  for (int idx = tid; idx < 16*64; idx += 256)
    attS[idx >> 6][idx & 63] = -9.0e15f;
  __syncthreads();

  int lane = tid & 63, wv = tid >> 6;       // wv = k
  int q = lane >> 4, c = lane & 15;

  // ---- E tile: A = (h .* a_wv) rows mi*16+c ; B = h rows ni*16+c ----
  f32x4 Eacc[4];
  #pragma unroll
  for (int ni = 0; ni < 4; ni++) Eacc[ni] = (f32x4){0.f,0.f,0.f,0.f};
  #pragma unroll
  for (int kt = 0; kt < 4; kt++){
    uint4 av = *(const uint4*)(alocb + wv*D_ + kt*32 + q*8);
    const uint32_t* ap = (const uint32_t*)&av;
    uint4 hv = *(const uint4*)(&hS[mi*16 + c][kt*32 + q*8]);
    const uint32_t* hp = (const uint32_t*)&hv;
    union { ushort_t u[8]; bf16x8 v; } afr;
    #pragma unroll
    for (int p = 0; p < 4; p++){
      float x0 = __uint_as_float(hp[p] << 16)         * __uint_as_float(ap[p] << 16);
      float x1 = __uint_as_float(hp[p] & 0xffff0000u) * __uint_as_float(ap[p] & 0xffff0000u);
      afr.u[2*p]   = f2bf(x0);
      afr.u[2*p+1] = f2bf(x1);
    }
    #pragma unroll
    for (int ni = 0; ni < 4; ni++){
      union { uint4 q4; bf16x8 v; } bfr;
      bfr.q4 = *(const uint4*)(&hS[ni*16 + c][kt*32 + q*8]);
      Eacc[ni] = __builtin_amdgcn_mfma_f32_16x16x32_bf16(afr.v, bfr.v, Eacc[ni], 0,0,0);
    }
  }
  // scatter: att[i][j] = leaky(E) where adj == wv+1
  const int* adjb = adj + (size_t)b*S_*S_;
  #pragma unroll
  for (int ni = 0; ni < 4; ni++){
    int j = ni*16 + c;
    #pragma unroll
    for (int r = 0; r < 4; r++){
      int i = mi*16 + q*4 + r;
      if (i < S_ && j < S_){
        int kk = adjb[i*S_ + j];
        if (kk == wv + 1) attS[q*4 + r][j] = leaky(Eacc[ni][r]);
      }
    }
  }
  __syncthreads();
  // softmax per row (threads 0..15)
  if (tid < 16){
    int i = mi*16 + tid;
    if (i < S_){
      float mx = -__builtin_inff();
      for (int j = 0; j < S_; j++) mx = fmaxf(mx, attS[tid][j]);
      float s = 0.f;
      for (int j = 0; j < S_; j++){ float e = __expf(attS[tid][j] - mx); attS[tid][j] = e; s += e; }
      float inv = 1.f / s;
      for (int j = 0; j < S_; j++) attS[tid][j] *= inv;
      for (int j = S_; j < 64; j++) attS[tid][j] = 0.f;
    } else {
      for (int j = 0; j < 64; j++) attS[tid][j] = 0.f;
    }
  }
  __syncthreads();
  // ---- P = att_tile @ h ; wave wv covers d-tiles {2wv, 2wv+1} ----
  f32x4 Pacc[2];
  Pacc[0] = (f32x4){0.f,0.f,0.f,0.f};
  Pacc[1] = (f32x4){0.f,0.f,0.f,0.f};
  #pragma unroll
  for (int kt = 0; kt < 2; kt++){
    union { ushort_t u[8]; bf16x8 v; } afr;
    const float* arow = &attS[c][kt*32 + q*8];
    #pragma unroll
    for (int j = 0; j < 8; j++) afr.u[j] = f2bf(arow[j]);
    #pragma unroll
    for (int nn = 0; nn < 2; nn++){
      int ni = 2*wv + nn;
      union { ushort_t u[8]; bf16x8 v; } bfr;
      #pragma unroll
      for (int jj = 0; jj < 8; jj++)
        bfr.u[jj] = hS[kt*32 + q*8 + jj][ni*16 + c];   // B[k=j][n=d]
      Pacc[nn] = __builtin_amdgcn_mfma_f32_16x16x32_bf16(afr.v, bfr.v, Pacc[nn], 0,0,0);
    }
  }
  #pragma unroll
  for (int nn = 0; nn < 2; nn++){
    int d = (2*wv + nn)*16 + c;
    #pragma unroll
    for (int r = 0; r < 4; r++){
      int i = mi*16 + q*4 + r;
      if (i < S_) hlb[((size_t)b*S_ + i)*D_ + d] = f2bf(Pacc[nn][r]);
    }
  }
}

// ---- merged score A+B: rows [0,nA) A-mode, [nA,3nA) B-mode ----------------
// B-frags of w1 read directly from pre-swizzled global w1f (L2-resident).
__global__ __launch_bounds__(256) void score_mfma_ab(
    const ushort_t* __restrict__ sessb, const ushort_t* __restrict__ emb,
    const int* __restrict__ neigh1, const int* __restrict__ adj_all,
    const uint4* __restrict__ w1f, const ushort_t* __restrict__ w2,
    float* __restrict__ score, int nA){
  int tid = threadIdx.x;
  int lane = tid & 63, wave = tid >> 6;
  int m = lane & 15, q = lane >> 4;
  float w2v[8];
  #pragma unroll
  for (int t = 0; t < 8; t++) w2v[t] = bf2f(w2[16*t + m]);

  for (int it = 0; it < 2; it++){
    int row_base = blockIdx.x*128 + it*64 + wave*16;
    int row = row_base + m;
    const ushort_t* nrow; int b;
    if (row < nA){
      nrow = emb + (size_t)neigh1[row]*D_;
      b = row / 600;
    } else {
      int r2 = row - nA;
      nrow = emb + (size_t)adj_all[(size_t)neigh1[r2>>1]*2 + (r2&1)]*D_;
      b = r2 / 1200;
    }
    const ushort_t* srow = sessb + (size_t)b*D_;

    f32x4 acc[8];
    #pragma unroll
    for (int t = 0; t < 8; t++) acc[t] = (f32x4){0.f,0.f,0.f,0.f};
    #pragma unroll
    for (int kt = 0; kt < 4; kt++){
      uint4 nv = *(const uint4*)(nrow + kt*32 + q*8);
      uint4 sv = *(const uint4*)(srow + kt*32 + q*8);
      const uint32_t* np = (const uint32_t*)&nv;
      const uint32_t* sp = (const uint32_t*)&sv;
      union { ushort_t u[8]; bf16x8 v; } afr;
      #pragma unroll
      for (int p = 0; p < 4; p++){
        uint32_t n2 = np[p], s2 = sp[p];
        float a0 = __uint_as_float(n2 << 16)          * __uint_as_float(s2 << 16);
        float a1 = __uint_as_float(n2 & 0xffff0000u)  * __uint_as_float(s2 & 0xffff0000u);
        afr.u[2*p]   = f2bf(a0);
        afr.u[2*p+1] = f2bf(a1);
      }
      #pragma unroll
      for (int t = 0; t < 8; t++){
        union { uint4 q4; bf16x8 v; } bfr;
        bfr.q4 = w1f[(kt*8 + t)*64 + lane];
        acc[t] = __builtin_amdgcn_mfma_f32_16x16x32_bf16(afr.v, bfr.v, acc[t], 0, 0, 0);
      }
    }
    #pragma unroll
    for (int r = 0; r < 4; r++){
      float s = 0.f;
      #pragma unroll
      for (int t = 0; t < 8; t++) s += leaky(acc[t][r]) * w2v[t];
      s += __shfl_xor(s, 1, 64);
      s += __shfl_xor(s, 2, 64);
      s += __shfl_xor(s, 4, 64);
      s += __shfl_xor(s, 8, 64);
      if (m == 0) score[row_base + q*4 + r] = s;
    }
  }
}

// ---- score C: neigh = out1[row] -------------------------------------------
__global__ __launch_bounds__(256) void score_mfma_c(
    const ushort_t* __restrict__ sessb, const ushort_t* __restrict__ out1,
    const uint4* __restrict__ w1f, const ushort_t* __restrict__ w2,
    float* __restrict__ score){
  int tid = threadIdx.x;
  int lane = tid & 63, wave = tid >> 6;
  int m = lane & 15, q = lane >> 4;
  float w2v[8];
  #pragma unroll
  for (int t = 0; t < 8; t++) w2v[t] = bf2f(w2[16*t + m]);
  for (int it = 0; it < 2; it++){
    int row_base = blockIdx.x*128 + it*64 + wave*16;
    int row = row_base + m;
    const ushort_t* nrow = out1 + (size_t)row*D_;
    int b = row / 600;
    const ushort_t* srow = sessb + (size_t)b*D_;
    f32x4 acc[8];
    #pragma unroll
    for (int t = 0; t < 8; t++) acc[t] = (f32x4){0.f,0.f,0.f,0.f};
    #pragma unroll
    for (int kt = 0; kt < 4; kt++){
      uint4 nv = *(const uint4*)(nrow + kt*32 + q*8);
      uint4 sv = *(const uint4*)(srow + kt*32 + q*8);
      const uint32_t* np = (const uint32_t*)&nv;
      const uint32_t* sp = (const uint32_t*)&sv;
      union { ushort_t u[8]; bf16x8 v; } afr;
      #pragma unroll
      for (int p = 0; p < 4; p++){
        uint32_t n2 = np[p], s2 = sp[p];
        float a0 = __uint_as_float(n2 << 16)          * __uint_as_float(s2 << 16);
        float a1 = __uint_as_float(n2 & 0xffff0000u)  * __uint_as_float(s2 & 0xffff0000u);
        afr.u[2*p]   = f2bf(a0);
        afr.u[2*p+1] = f2bf(a1);
      }
      #pragma unroll
      for (int t = 0; t < 8; t++){
        union { uint4 q4; bf16x8 v; } bfr;
        bfr.q4 = w1f[(kt*8 + t)*64 + lane];
        acc[t] = __builtin_amdgcn_mfma_f32_16x16x32_bf16(afr.v, bfr.v, acc[t], 0, 0, 0);
      }
    }
    #pragma unroll
    for (int r = 0; r < 4; r++){
      float s = 0.f;
      #pragma unroll
      for (int t = 0; t < 8; t++) s += leaky(acc[t][r]) * w2v[t];
      s += __shfl_xor(s, 1, 64);
      s += __shfl_xor(s, 2, 64);
      s += __shfl_xor(s, 4, 64);
      s += __shfl_xor(s, 8, 64);
      if (m == 0) score[row_base + q*4 + r] = s;
    }
  }
}

// ---- shared out helpers ---------------------------------------------------
template<int K>
__device__ __forceinline__ void softmaxK(const float* __restrict__ sc, float att[K]){
  float mx = -__builtin_inff();
  #pragma unroll
  for (int k = 0; k < K; k++){ att[k] = sc[k]; mx = fmaxf(mx, att[k]); }
  float s = 0.f;
  #pragma unroll
  for (int k = 0; k < K; k++){ att[k] = __expf(att[k] - mx); s += att[k]; }
  float inv = 1.f / s;
  #pragma unroll
  for (int k = 0; k < K; k++) att[k] *= inv;
}

// A-frags of w3 read from pre-swizzled global w3f (L2-resident).
template<int K>
__device__ __forceinline__ void out_tile(
    int lane, const uint4* __restrict__ w3f,
    const ushort_t* __restrict__ sptr, const ushort_t* const nptr[K],
    const float att[K], f32x4 acc[8]){
  int q = lane >> 4;
  #pragma unroll
  for (int kt = 0; kt < 8; kt++){
    union { ushort_t u[8]; uint4 q4; bf16x8 v; } bfr;
    if (kt < 4){
      bfr.q4 = *(const uint4*)(sptr + kt*32 + q*8);
    } else {
      float g[8] = {0,0,0,0,0,0,0,0};
      #pragma unroll
      for (int k = 0; k < K; k++){
        uint4 nv = *(const uint4*)(nptr[k] + (kt-4)*32 + q*8);
        const uint32_t* np = (const uint32_t*)&nv;
        #pragma unroll
        for (int p = 0; p < 4; p++){
          g[2*p]   = fmaf(att[k], __uint_as_float(np[p] << 16),         g[2*p]);
          g[2*p+1] = fmaf(att[k], __uint_as_float(np[p] & 0xffff0000u), g[2*p+1]);
        }
      }
      #pragma unroll
      for (int j = 0; j < 8; j++) bfr.u[j] = f2bf(g[j]);
    }
    #pragma unroll
    for (int t = 0; t < 8; t++){
      union { uint4 q4; bf16x8 v; } af;
      af.q4 = w3f[(kt*8 + t)*64 + lane];
      acc[t] = __builtin_amdgcn_mfma_f32_16x16x32_bf16(af.v, bfr.v, acc[t], 0, 0, 0);
    }
  }
}

// ---- merged out A+B (full 128 cols; no LDS) -------------------------------
__global__ __launch_bounds__(256) void out_mfma_ab(
    const float* __restrict__ score, const int* __restrict__ idx,
    const int* __restrict__ nbr, const int* __restrict__ adj_all,
    const ushort_t* __restrict__ emb, const uint4* __restrict__ w3f,
    const ushort_t* __restrict__ bias,
    ushort_t* __restrict__ o0c, ushort_t* __restrict__ out1c,
    int nA, int nTot, int scoreBbase){
  int tid = threadIdx.x;
  int lane = tid & 63, wave = tid >> 6;
  int mrow = lane & 15, q = lane >> 4;
  float bv[8][4];
  #pragma unroll
  for (int t = 0; t < 8; t++){
    const ushort_t* bp = bias + 16*t + q*4;
    #pragma unroll
    for (int r = 0; r < 4; r++) bv[t][r] = bf2f(bp[r]);
  }
  for (int it = 0; it < 2; it++){
    int row_base = blockIdx.x*128 + it*64 + wave*16;
    int row = row_base + mrow;
    bool active = row < nTot;
    int rowc = active ? row : (nTot - 1);
    bool isA = rowc < nA;
    f32x4 acc[8];
    #pragma unroll
    for (int t = 0; t < 8; t++) acc[t] = (f32x4){0.f,0.f,0.f,0.f};
    if (isA){
      const ushort_t* sptr = emb + (size_t)idx[rowc]*D_;
      const ushort_t* nptr[12];
      #pragma unroll
      for (int k = 0; k < 12; k++) nptr[k] = emb + (size_t)nbr[rowc*12 + k]*D_;
      float att[12];
      softmaxK<12>(score + (size_t)rowc*12, att);
      out_tile<12>(lane, w3f, sptr, nptr, att, acc);
    } else {
      int rB = rowc - nA;
      const ushort_t* sptr = emb + (size_t)nbr[rB]*D_;
      const ushort_t* nptr[2];
      #pragma unroll
      for (int k = 0; k < 2; k++) nptr[k] = emb + (size_t)adj_all[(size_t)nbr[rB]*2 + k]*D_;
      float att[2];
      softmaxK<2>(score + scoreBbase + (size_t)rB*2, att);
      out_tile<2>(lane, w3f, sptr, nptr, att, acc);
    }
    if (active){
      ushort_t* dst = isA ? (o0c + (size_t)row*D_) : (out1c + (size_t)(row - nA)*D_);
      #pragma unroll
      for (int t = 0; t < 8; t++){
        int col0 = 16*t + q*4;
        union { ushort_t u[4]; uint2 d2; } pk;
        #pragma unroll
        for (int r = 0; r < 4; r++) pk.u[r] = f2bf(fmaxf(acc[t][r] + bv[t][r], 0.f));
        *(uint2*)(dst + col0) = pk.d2;
      }
    }
  }
}

// ---- out C: self=o0c[row], neigh=out1[row*12+k], +addsrc, f32 out ---------
__global__ __launch_bounds__(256) void out_mfma_c(
    const float* __restrict__ score, const ushort_t* __restrict__ out1,
    const ushort_t* __restrict__ selfsrc, const uint4* __restrict__ w3f,
    const ushort_t* __restrict__ bias,
    const ushort_t* __restrict__ addsrc, float* __restrict__ outf, int nrows){
  int tid = threadIdx.x;
  int lane = tid & 63, wave = tid >> 6;
  int mrow = lane & 15, q = lane >> 4;
  float bv[8][4];
  #pragma unroll
  for (int t = 0; t < 8; t++){
    const ushort_t* bp = bias + 16*t + q*4;
    #pragma unroll
    for (int r = 0; r < 4; r++) bv[t][r] = bf2f(bp[r]);
  }
  for (int it = 0; it < 2; it++){
    int row_base = blockIdx.x*128 + it*64 + wave*16;
    int row = row_base + mrow;
    bool active = row < nrows;
    int rowc = active ? row : (nrows - 1);
    const ushort_t* sptr = selfsrc + (size_t)rowc*D_;
    const ushort_t* nptr[12];
    #pragma unroll
    for (int k = 0; k < 12; k++) nptr[k] = out1 + (size_t)(rowc*12 + k)*D_;
    float att[12];
    softmaxK<12>(score + (size_t)rowc*12, att);
    f32x4 acc[8];
    #pragma unroll
    for (int t = 0; t < 8; t++) acc[t] = (f32x4){0.f,0.f,0.f,0.f};
    out_tile<12>(lane, w3f, sptr, nptr, att, acc);
    if (active){
      #pragma unroll
      for (int t = 0; t < 8; t++){
        int col0 = 16*t + q*4;
        float v[4];
        const ushort_t* ap = addsrc + (size_t)row*D_ + col0;
        #pragma unroll
        for (int r = 0; r < 4; r++)
          v[r] = fmaxf(acc[t][r] + bv[t][r], 0.f) + bf2f(ap[r]);
        *(f32x4*)(outf + (size_t)row*D_ + col0) = (f32x4){v[0], v[1], v[2], v[3]};
      }
    }
  }
}

extern "C" void kernel_launch(void* const* d_in, const int* in_sizes, int n_in,
                              void* d_out, int out_size, void* d_ws, size_t ws_size,
                              hipStream_t stream) {
  const int* inputs    = (const int*)d_in[0];
  const int* adj       = (const int*)d_in[1];
  const int* mask_item = (const int*)d_in[2];
  const int* item      = (const int*)d_in[3];
  const int* first_adj = (const int*)d_in[4];    // neigh1 (B,600)
  const int* adj_all   = (const int*)d_in[5];    // (50000,2)

  // ---- ws layout (bf16 block is contiguous for cvt_all) ----
  char* ws = (char*)d_ws;
  size_t o = 0;
  int*      flag   = (int*)(ws + o);      o += 64;
  ushort_t* emb_b  = (ushort_t*)(ws + o); o += 12800000;  // 50000*128
  ushort_t* alocb  = (ushort_t*)(ws + o); o += 1024;      // 4*128
  ushort_t* gw1b   = (ushort_t*)(ws + o); o += 65536;     // 2*128*128
  ushort_t* gw2b   = (ushort_t*)(ws + o); o += 512;       // 2*128
  ushort_t* gw3b   = (ushort_t*)(ws + o); o += 131072;    // 2*256*128
  ushort_t* gbb    = (ushort_t*)(ws + o); o += 512;       // 2*128
  ushort_t* sessb  = (ushort_t*)(ws + o); o += 32768;     // 128*128
  ushort_t* hlb    = (ushort_t*)(ws + o); o += 1638400;   // 6400*128
  uint4*    w1f    = (uint4*)(ws + o);    o += 65536;     // 2 hops x 2048 uint4
  uint4*    w3f    = (uint4*)(ws + o);    o += 131072;    // 2 hops x 4096 uint4
  size_t fixed = o;
  // variable: out1c CHB*153600 + o0c CHB*12800 + score CHB*7200 = CHB*173600
  int CHB = 16;
  if      (ws_size >= fixed + (size_t)128*173600) CHB = 128;
  else if (ws_size >= fixed + (size_t)64 *173600) CHB = 64;
  else if (ws_size >= fixed + (size_t)32 *173600) CHB = 32;
  ushort_t* out1c = (ushort_t*)(ws + o);  o += (size_t)CHB*153600;
  ushort_t* o0c   = (ushort_t*)(ws + o);  o += (size_t)CHB*12800;
  float*    score = (float*)(ws + o);

  float* outp = (float*)d_out;   // output is f32 storage

  // ---- dtype normalize + fragment pre-swizzle (3 launches) ----
  detect_kernel<<<1, 64, 0, stream>>>((const uint32_t*)d_in[6], flag);
  cvt_all<<<(6499328/4 + 255)/256, 256, 0, stream>>>(d_in[6], d_in[7], d_in[8], d_in[9],
                                                     d_in[10], d_in[11], emb_b, flag);
  prep_frags<<<48, 256, 0, stream>>>(gw1b, gw3b, w1f, w3f);

  sess_kernel<<<B_, 128, 0, stream>>>(item, mask_item, emb_b, sessb);
  local_mfma2<<<B_*4, 256, 0, stream>>>(inputs, adj, emb_b, alocb, hlb);

  int nchunk = B_ / CHB;
  for (int c = 0; c < nchunk; c++){
    int b0 = c * CHB;
    const int* fadj  = first_adj + (size_t)b0 * 600;
    const ushort_t* sbc = sessb + (size_t)b0 * D_;
    ushort_t*  hlc   = hlb  + (size_t)b0 * 50 * D_;
    float*     outc  = outp + (size_t)b0 * 50 * D_;
    int nA600 = CHB*600, nA50 = CHB*50, nTot = CHB*650;

    // scores A (rows [0,nA600)) + B (rows [nA600, 3*nA600))
    score_mfma_ab<<<(3*nA600)/128, 256, 0, stream>>>(sbc, emb_b, fadj, adj_all,
                                                     w1f, gw2b, score, nA600);
    // out A (-> o0c) + B (-> out1c)
    out_mfma_ab<<<(nTot + 127)/128, 256, 0, stream>>>(score, inputs + b0*50, fadj, adj_all,
                                                      emb_b, w3f, gbb, o0c, out1c,
                                                      nA50, nTot, nA600);
    // scores C (rows [0,nA600))
    score_mfma_c<<<nA600/128, 256, 0, stream>>>(sbc, out1c, w1f + 2048, gw2b + 128, score);
    // out C -> d_out (f32, + h_local)
    out_mfma_c<<<(nA50 + 127)/128, 256, 0, stream>>>(score, out1c, o0c,
                                                     w3f + 4096, gbb + 128,
                                                     hlc, outc, nA50);
  }
}

// Round 15
// 199.375 us; speedup vs baseline: 1.4304x; 1.4304x over previous
//
#include <hip/hip_runtime.h>
#include <stdint.h>

typedef unsigned short ushort_t;
typedef __attribute__((ext_vector_type(8))) short bf16x8;   // 4 VGPRs, 8 bf16
typedef __attribute__((ext_vector_type(4))) float f32x4;    // MFMA C/D

#define B_   128
#define S_   50
#define D_   128
#define ALPHA_ 0.2f

__device__ __forceinline__ float bf2f(ushort_t u){
  return __uint_as_float(((uint32_t)u) << 16);
}
__device__ __forceinline__ ushort_t f2bf(float f){
  uint32_t x = __float_as_uint(f);
  x = (x + 0x7fffu + ((x >> 16) & 1u)) >> 16;
  return (ushort_t)x;
}
__device__ __forceinline__ float leaky(float x){ return x >= 0.f ? x : ALPHA_*x; }

// ---- detect: are float inputs bf16-packed (flag=1) or f32 (flag=0)? -------
__global__ void detect_kernel(const uint32_t* __restrict__ emb_raw, int* __restrict__ flag){
  if (threadIdx.x == 0 && blockIdx.x == 0){
    int ok = 1;
    for (int i = 0; i < 64; i++){
      uint32_t lo = emb_raw[i] & 0xffffu;
      uint32_t ex = (lo >> 7) & 0xFFu;
      if (!(lo == 0u || (ex >= 64u && ex <= 126u))) ok = 0;
    }
    *flag = ok;
  }
}

// ---- cvt_all: all six float tensors -> contiguous bf16 dst ----------------
__global__ void cvt_all(const void* __restrict__ p0, const void* __restrict__ p1,
                        const void* __restrict__ p2, const void* __restrict__ p3,
                        const void* __restrict__ p4, const void* __restrict__ p5,
                        ushort_t* __restrict__ dst, const int* __restrict__ flag){
  const int seg_end[6] = {6400000, 6400512, 6433280, 6433536, 6499072, 6499328};
  int base = (blockIdx.x*256 + threadIdx.x) * 4;
  if (base >= 6499328) return;
  int s = 0;
  while (base >= seg_end[s]) s++;
  int segbase = (s == 0) ? 0 : seg_end[s-1];
  const void* src = (s==0)?p0:(s==1)?p1:(s==2)?p2:(s==3)?p3:(s==4)?p4:p5;
  int off = base - segbase;
  union { ushort_t u[4]; uint2 d2; } o;
  if (*flag){
    o.d2 = *(const uint2*)((const ushort_t*)src + off);
  } else {
    float4 v = *(const float4*)((const float*)src + off);
    o.u[0] = f2bf(v.x); o.u[1] = f2bf(v.y); o.u[2] = f2bf(v.z); o.u[3] = f2bf(v.w);
  }
  *(uint2*)(dst + base) = o.d2;
}

// ---- prep_frags: pre-swizzle w1 (B-frag order) and w3 (A-frag order) ------
__global__ void prep_frags(const ushort_t* __restrict__ w1, const ushort_t* __restrict__ w3,
                           uint4* __restrict__ w1f, uint4* __restrict__ w3f){
  int id = blockIdx.x*256 + threadIdx.x;   // total 12288
  if (id >= 12288) return;
  if (id < 4096){
    int h = id >> 11, i = id & 2047;
    int kt = i >> 9, rem = i & 511, t = rem >> 6, ln = rem & 63;
    int q = ln >> 4, c = ln & 15;
    const ushort_t* w = w1 + h*16384;
    union { ushort_t u[8]; uint4 q4; } e;
    #pragma unroll
    for (int j = 0; j < 8; j++)
      e.u[j] = w[(32*kt + q*8 + j)*128 + 16*t + c];
    w1f[h*2048 + i] = e.q4;
  } else {
    int id2 = id - 4096;
    int h = id2 >> 12, i = id2 & 4095;
    int kt = i >> 9, rem = i & 511, t = rem >> 6, ln = rem & 63;
    int q = ln >> 4, c = ln & 15;
    const ushort_t* w = w3 + h*32768;
    union { ushort_t u[8]; uint4 q4; } e;
    #pragma unroll
    for (int j = 0; j < 8; j++)
      e.u[j] = w[(32*kt + q*8 + j)*128 + 16*t + c];
    w3f[h*4096 + i] = e.q4;
  }
}

// ---- sess: masked mean of item embeddings -> bf16 (B,D) -------------------
__global__ void sess_kernel(const int* __restrict__ item, const int* __restrict__ mask,
                            const ushort_t* __restrict__ emb, ushort_t* __restrict__ sessb){
  int b = blockIdx.x, d = threadIdx.x;
  float acc = 0.f, den = 0.f;
  for (int s = 0; s < S_; s++){
    float fm = (float)mask[b*S_ + s];
    int id = item[b*S_ + s];
    acc += fm * bf2f(emb[(size_t)id*D_ + d]);
    den += fm;
  }
  sessb[b*D_ + d] = f2bf(acc / den);
}

// ---- local attention via MFMA: one block per (b, mi) 16-row i-tile --------
__global__ __launch_bounds__(256) void local_mfma2(
    const int* __restrict__ inputs, const int* __restrict__ adj,
    const ushort_t* __restrict__ emb, const ushort_t* __restrict__ alocb,
    ushort_t* __restrict__ hlb){
  __shared__ ushort_t hS[64][136];   // h[j][d], row stride 272B
  __shared__ float    attS[16][68];  // att tile
  __shared__ int      sids[64];
  int blk = blockIdx.x;
  int b  = blk >> 2;
  int mi = blk & 3;                  // i-tile: rows mi*16 .. mi*16+15
  int tid = threadIdx.x;
  if (tid < 64) sids[tid] = (tid < S_) ? inputs[b*S_ + tid] : 0;
  __syncthreads();
  for (int idx = tid; idx < 64*16; idx += 256){
    int j = idx >> 4, ch = idx & 15;
    uint4 v = {0u, 0u, 0u, 0u};
    if (j < S_) v = *(const uint4*)(emb + (size_t)sids[j]*D_ + ch*8);
    *(uint4*)(&hS[j][ch*8]) = v;
  }
  for (int idx = tid; idx < 16*64; idx += 256)
    attS[idx >> 6][idx & 63] = -9.0e15f;
  __syncthreads();

  int lane = tid & 63, wv = tid >> 6;       // wv = k
  int q = lane >> 4, c = lane & 15;

  f32x4 Eacc[4];
  #pragma unroll
  for (int ni = 0; ni < 4; ni++) Eacc[ni] = (f32x4){0.f,0.f,0.f,0.f};
  #pragma unroll
  for (int kt = 0; kt < 4; kt++){
    uint4 av = *(const uint4*)(alocb + wv*D_ + kt*32 + q*8);
    const uint32_t* ap = (const uint32_t*)&av;
    uint4 hv = *(const uint4*)(&hS[mi*16 + c][kt*32 + q*8]);
    const uint32_t* hp = (const uint32_t*)&hv;
    union { ushort_t u[8]; bf16x8 v; } afr;
    #pragma unroll
    for (int p = 0; p < 4; p++){
      float x0 = __uint_as_float(hp[p] << 16)         * __uint_as_float(ap[p] << 16);
      float x1 = __uint_as_float(hp[p] & 0xffff0000u) * __uint_as_float(ap[p] & 0xffff0000u);
      afr.u[2*p]   = f2bf(x0);
      afr.u[2*p+1] = f2bf(x1);
    }
    #pragma unroll
    for (int ni = 0; ni < 4; ni++){
      union { uint4 q4; bf16x8 v; } bfr;
      bfr.q4 = *(const uint4*)(&hS[ni*16 + c][kt*32 + q*8]);
      Eacc[ni] = __builtin_amdgcn_mfma_f32_16x16x32_bf16(afr.v, bfr.v, Eacc[ni], 0,0,0);
    }
  }
  const int* adjb = adj + (size_t)b*S_*S_;
  #pragma unroll
  for (int ni = 0; ni < 4; ni++){
    int j = ni*16 + c;
    #pragma unroll
    for (int r = 0; r < 4; r++){
      int i = mi*16 + q*4 + r;
      if (i < S_ && j < S_){
        int kk = adjb[i*S_ + j];
        if (kk == wv + 1) attS[q*4 + r][j] = leaky(Eacc[ni][r]);
      }
    }
  }
  __syncthreads();
  if (tid < 16){
    int i = mi*16 + tid;
    if (i < S_){
      float mx = -__builtin_inff();
      for (int j = 0; j < S_; j++) mx = fmaxf(mx, attS[tid][j]);
      float s = 0.f;
      for (int j = 0; j < S_; j++){ float e = __expf(attS[tid][j] - mx); attS[tid][j] = e; s += e; }
      float inv = 1.f / s;
      for (int j = 0; j < S_; j++) attS[tid][j] *= inv;
      for (int j = S_; j < 64; j++) attS[tid][j] = 0.f;
    } else {
      for (int j = 0; j < 64; j++) attS[tid][j] = 0.f;
    }
  }
  __syncthreads();
  f32x4 Pacc[2];
  Pacc[0] = (f32x4){0.f,0.f,0.f,0.f};
  Pacc[1] = (f32x4){0.f,0.f,0.f,0.f};
  #pragma unroll
  for (int kt = 0; kt < 2; kt++){
    union { ushort_t u[8]; bf16x8 v; } afr;
    const float* arow = &attS[c][kt*32 + q*8];
    #pragma unroll
    for (int j = 0; j < 8; j++) afr.u[j] = f2bf(arow[j]);
    #pragma unroll
    for (int nn = 0; nn < 2; nn++){
      int ni = 2*wv + nn;
      union { ushort_t u[8]; bf16x8 v; } bfr;
      #pragma unroll
      for (int jj = 0; jj < 8; jj++)
        bfr.u[jj] = hS[kt*32 + q*8 + jj][ni*16 + c];
      Pacc[nn] = __builtin_amdgcn_mfma_f32_16x16x32_bf16(afr.v, bfr.v, Pacc[nn], 0,0,0);
    }
  }
  #pragma unroll
  for (int nn = 0; nn < 2; nn++){
    int d = (2*wv + nn)*16 + c;
    #pragma unroll
    for (int r = 0; r < 4; r++){
      int i = mi*16 + q*4 + r;
      if (i < S_) hlb[((size_t)b*S_ + i)*D_ + d] = f2bf(Pacc[nn][r]);
    }
  }
}

// ---- merged score A+B: rows [0,nA) A-mode, [nA,3nA) B-mode ----------------
__global__ __launch_bounds__(256) void score_mfma_ab(
    const ushort_t* __restrict__ sessb, const ushort_t* __restrict__ emb,
    const int* __restrict__ neigh1, const int* __restrict__ adj_all,
    const uint4* __restrict__ w1f, const ushort_t* __restrict__ w2,
    float* __restrict__ score, int nA){
  __shared__ uint4 bfrag[2048];      // 32 KB, coalesced copy from w1f
  int tid = threadIdx.x;
  for (int i = tid; i < 2048; i += 256) bfrag[i] = w1f[i];
  __syncthreads();
  int lane = tid & 63, wave = tid >> 6;
  int m = lane & 15, q = lane >> 4;
  float w2v[8];
  #pragma unroll
  for (int t = 0; t < 8; t++) w2v[t] = bf2f(w2[16*t + m]);

  for (int it = 0; it < 2; it++){
    int row_base = blockIdx.x*128 + it*64 + wave*16;
    int row = row_base + m;
    const ushort_t* nrow; int b;
    if (row < nA){
      nrow = emb + (size_t)neigh1[row]*D_;
      b = row / 600;
    } else {
      int r2 = row - nA;
      nrow = emb + (size_t)adj_all[(size_t)neigh1[r2>>1]*2 + (r2&1)]*D_;
      b = r2 / 1200;
    }
    const ushort_t* srow = sessb + (size_t)b*D_;

    f32x4 acc[8];
    #pragma unroll
    for (int t = 0; t < 8; t++) acc[t] = (f32x4){0.f,0.f,0.f,0.f};
    #pragma unroll
    for (int kt = 0; kt < 4; kt++){
      uint4 nv = *(const uint4*)(nrow + kt*32 + q*8);
      uint4 sv = *(const uint4*)(srow + kt*32 + q*8);
      const uint32_t* np = (const uint32_t*)&nv;
      const uint32_t* sp = (const uint32_t*)&sv;
      union { ushort_t u[8]; bf16x8 v; } afr;
      #pragma unroll
      for (int p = 0; p < 4; p++){
        uint32_t n2 = np[p], s2 = sp[p];
        float a0 = __uint_as_float(n2 << 16)          * __uint_as_float(s2 << 16);
        float a1 = __uint_as_float(n2 & 0xffff0000u)  * __uint_as_float(s2 & 0xffff0000u);
        afr.u[2*p]   = f2bf(a0);
        afr.u[2*p+1] = f2bf(a1);
      }
      #pragma unroll
      for (int t = 0; t < 8; t++){
        union { uint4 q4; bf16x8 v; } bfr;
        bfr.q4 = bfrag[(kt*8 + t)*64 + lane];
        acc[t] = __builtin_amdgcn_mfma_f32_16x16x32_bf16(afr.v, bfr.v, acc[t], 0, 0, 0);
      }
    }
    #pragma unroll
    for (int r = 0; r < 4; r++){
      float s = 0.f;
      #pragma unroll
      for (int t = 0; t < 8; t++) s += leaky(acc[t][r]) * w2v[t];
      s += __shfl_xor(s, 1, 64);
      s += __shfl_xor(s, 2, 64);
      s += __shfl_xor(s, 4, 64);
      s += __shfl_xor(s, 8, 64);
      if (m == 0) score[row_base + q*4 + r] = s;
    }
  }
}

// ---- score C: neigh = out1[row] -------------------------------------------
__global__ __launch_bounds__(256) void score_mfma_c(
    const ushort_t* __restrict__ sessb, const ushort_t* __restrict__ out1,
    const uint4* __restrict__ w1f, const ushort_t* __restrict__ w2,
    float* __restrict__ score){
  __shared__ uint4 bfrag[2048];
  int tid = threadIdx.x;
  for (int i = tid; i < 2048; i += 256) bfrag[i] = w1f[i];
  __syncthreads();
  int lane = tid & 63, wave = tid >> 6;
  int m = lane & 15, q = lane >> 4;
  float w2v[8];
  #pragma unroll
  for (int t = 0; t < 8; t++) w2v[t] = bf2f(w2[16*t + m]);
  for (int it = 0; it < 2; it++){
    int row_base = blockIdx.x*128 + it*64 + wave*16;
    int row = row_base + m;
    const ushort_t* nrow = out1 + (size_t)row*D_;
    int b = row / 600;
    const ushort_t* srow = sessb + (size_t)b*D_;
    f32x4 acc[8];
    #pragma unroll
    for (int t = 0; t < 8; t++) acc[t] = (f32x4){0.f,0.f,0.f,0.f};
    #pragma unroll
    for (int kt = 0; kt < 4; kt++){
      uint4 nv = *(const uint4*)(nrow + kt*32 + q*8);
      uint4 sv = *(const uint4*)(srow + kt*32 + q*8);
      const uint32_t* np = (const uint32_t*)&nv;
      const uint32_t* sp = (const uint32_t*)&sv;
      union { ushort_t u[8]; bf16x8 v; } afr;
      #pragma unroll
      for (int p = 0; p < 4; p++){
        uint32_t n2 = np[p], s2 = sp[p];
        float a0 = __uint_as_float(n2 << 16)          * __uint_as_float(s2 << 16);
        float a1 = __uint_as_float(n2 & 0xffff0000u)  * __uint_as_float(s2 & 0xffff0000u);
        afr.u[2*p]   = f2bf(a0);
        afr.u[2*p+1] = f2bf(a1);
      }
      #pragma unroll
      for (int t = 0; t < 8; t++){
        union { uint4 q4; bf16x8 v; } bfr;
        bfr.q4 = bfrag[(kt*8 + t)*64 + lane];
        acc[t] = __builtin_amdgcn_mfma_f32_16x16x32_bf16(afr.v, bfr.v, acc[t], 0, 0, 0);
      }
    }
    #pragma unroll
    for (int r = 0; r < 4; r++){
      float s = 0.f;
      #pragma unroll
      for (int t = 0; t < 8; t++) s += leaky(acc[t][r]) * w2v[t];
      s += __shfl_xor(s, 1, 64);
      s += __shfl_xor(s, 2, 64);
      s += __shfl_xor(s, 4, 64);
      s += __shfl_xor(s, 8, 64);
      if (m == 0) score[row_base + q*4 + r] = s;
    }
  }
}

// ---- shared out helpers ---------------------------------------------------
template<int K>
__device__ __forceinline__ void softmaxK(const float* __restrict__ sc, float att[K]){
  float mx = -__builtin_inff();
  #pragma unroll
  for (int k = 0; k < K; k++){ att[k] = sc[k]; mx = fmaxf(mx, att[k]); }
  float s = 0.f;
  #pragma unroll
  for (int k = 0; k < K; k++){ att[k] = __expf(att[k] - mx); s += att[k]; }
  float inv = 1.f / s;
  #pragma unroll
  for (int k = 0; k < K; k++) att[k] *= inv;
}

template<int K>
__device__ __forceinline__ void out_tile(
    int lane, const uint4* __restrict__ afrag,
    const ushort_t* __restrict__ sptr, const ushort_t* const nptr[K],
    const float att[K], f32x4 acc[8]){
  int q = lane >> 4;
  #pragma unroll
  for (int kt = 0; kt < 8; kt++){
    union { ushort_t u[8]; uint4 q4; bf16x8 v; } bfr;
    if (kt < 4){
      bfr.q4 = *(const uint4*)(sptr + kt*32 + q*8);
    } else {
      float g[8] = {0,0,0,0,0,0,0,0};
      #pragma unroll
      for (int k = 0; k < K; k++){
        uint4 nv = *(const uint4*)(nptr[k] + (kt-4)*32 + q*8);
        const uint32_t* np = (const uint32_t*)&nv;
        #pragma unroll
        for (int p = 0; p < 4; p++){
          g[2*p]   = fmaf(att[k], __uint_as_float(np[p] << 16),         g[2*p]);
          g[2*p+1] = fmaf(att[k], __uint_as_float(np[p] & 0xffff0000u), g[2*p+1]);
        }
      }
      #pragma unroll
      for (int j = 0; j < 8; j++) bfr.u[j] = f2bf(g[j]);
    }
    #pragma unroll
    for (int t = 0; t < 8; t++){
      union { uint4 q4; bf16x8 v; } af;
      af.q4 = afrag[(kt*8 + t)*64 + lane];
      acc[t] = __builtin_amdgcn_mfma_f32_16x16x32_bf16(af.v, bfr.v, acc[t], 0, 0, 0);
    }
  }
}

// ---- merged out A+B: 512 threads (8 waves share 64 KB w3 LDS), 128 rows/blk
__global__ __launch_bounds__(512) void out_mfma_ab(
    const float* __restrict__ score, const int* __restrict__ idx,
    const int* __restrict__ nbr, const int* __restrict__ adj_all,
    const ushort_t* __restrict__ emb, const uint4* __restrict__ w3f,
    const ushort_t* __restrict__ bias,
    ushort_t* __restrict__ o0c, ushort_t* __restrict__ out1c,
    int nA, int nTot, int scoreBbase){
  __shared__ uint4 afrag[4096];   // 64 KB, coalesced copy from w3f
  int tid = threadIdx.x;
  for (int i = tid; i < 4096; i += 512) afrag[i] = w3f[i];
  __syncthreads();
  int lane = tid & 63, wave = tid >> 6;   // 8 waves
  int mrow = lane & 15, q = lane >> 4;
  float bv[8][4];
  #pragma unroll
  for (int t = 0; t < 8; t++){
    const ushort_t* bp = bias + 16*t + q*4;
    #pragma unroll
    for (int r = 0; r < 4; r++) bv[t][r] = bf2f(bp[r]);
  }
  int row_base = blockIdx.x*128 + wave*16;
  int row = row_base + mrow;
  bool active = row < nTot;
  int rowc = active ? row : (nTot - 1);
  bool isA = rowc < nA;
  f32x4 acc[8];
  #pragma unroll
  for (int t = 0; t < 8; t++) acc[t] = (f32x4){0.f,0.f,0.f,0.f};
  if (isA){
    const ushort_t* sptr = emb + (size_t)idx[rowc]*D_;
    const ushort_t* nptr[12];
    #pragma unroll
    for (int k = 0; k < 12; k++) nptr[k] = emb + (size_t)nbr[rowc*12 + k]*D_;
    float att[12];
    softmaxK<12>(score + (size_t)rowc*12, att);
    out_tile<12>(lane, afrag, sptr, nptr, att, acc);
  } else {
    int rB = rowc - nA;
    const ushort_t* sptr = emb + (size_t)nbr[rB]*D_;
    const ushort_t* nptr[2];
    #pragma unroll
    for (int k = 0; k < 2; k++) nptr[k] = emb + (size_t)adj_all[(size_t)nbr[rB]*2 + k]*D_;
    float att[2];
    softmaxK<2>(score + scoreBbase + (size_t)rB*2, att);
    out_tile<2>(lane, afrag, sptr, nptr, att, acc);
  }
  if (active){
    ushort_t* dst = isA ? (o0c + (size_t)row*D_) : (out1c + (size_t)(row - nA)*D_);
    #pragma unroll
    for (int t = 0; t < 8; t++){
      int col0 = 16*t + q*4;
      union { ushort_t u[4]; uint2 d2; } pk;
      #pragma unroll
      for (int r = 0; r < 4; r++) pk.u[r] = f2bf(fmaxf(acc[t][r] + bv[t][r], 0.f));
      *(uint2*)(dst + col0) = pk.d2;
    }
  }
}

// ---- out C: 512 threads, self=o0c[row], neigh=out1[row*12+k], f32 out -----
__global__ __launch_bounds__(512) void out_mfma_c(
    const float* __restrict__ score, const ushort_t* __restrict__ out1,
    const ushort_t* __restrict__ selfsrc, const uint4* __restrict__ w3f,
    const ushort_t* __restrict__ bias,
    const ushort_t* __restrict__ addsrc, float* __restrict__ outf, int nrows){
  __shared__ uint4 afrag[4096];
  int tid = threadIdx.x;
  for (int i = tid; i < 4096; i += 512) afrag[i] = w3f[i];
  __syncthreads();
  int lane = tid & 63, wave = tid >> 6;
  int mrow = lane & 15, q = lane >> 4;
  float bv[8][4];
  #pragma unroll
  for (int t = 0; t < 8; t++){
    const ushort_t* bp = bias + 16*t + q*4;
    #pragma unroll
    for (int r = 0; r < 4; r++) bv[t][r] = bf2f(bp[r]);
  }
  int row_base = blockIdx.x*128 + wave*16;
  int row = row_base + mrow;
  bool active = row < nrows;
  int rowc = active ? row : (nrows - 1);
  const ushort_t* sptr = selfsrc + (size_t)rowc*D_;
  const ushort_t* nptr[12];
  #pragma unroll
  for (int k = 0; k < 12; k++) nptr[k] = out1 + (size_t)(rowc*12 + k)*D_;
  float att[12];
  softmaxK<12>(score + (size_t)rowc*12, att);
  f32x4 acc[8];
  #pragma unroll
  for (int t = 0; t < 8; t++) acc[t] = (f32x4){0.f,0.f,0.f,0.f};
  out_tile<12>(lane, afrag, sptr, nptr, att, acc);
  if (active){
    #pragma unroll
    for (int t = 0; t < 8; t++){
      int col0 = 16*t + q*4;
      float v[4];
      const ushort_t* ap = addsrc + (size_t)row*D_ + col0;
      #pragma unroll
      for (int r = 0; r < 4; r++)
        v[r] = fmaxf(acc[t][r] + bv[t][r], 0.f) + bf2f(ap[r]);
      *(f32x4*)(outf + (size_t)row*D_ + col0) = (f32x4){v[0], v[1], v[2], v[3]};
    }
  }
}

extern "C" void kernel_launch(void* const* d_in, const int* in_sizes, int n_in,
                              void* d_out, int out_size, void* d_ws, size_t ws_size,
                              hipStream_t stream) {
  const int* inputs    = (const int*)d_in[0];
  const int* adj       = (const int*)d_in[1];
  const int* mask_item = (const int*)d_in[2];
  const int* item      = (const int*)d_in[3];
  const int* first_adj = (const int*)d_in[4];    // neigh1 (B,600)
  const int* adj_all   = (const int*)d_in[5];    // (50000,2)

  // ---- ws layout (bf16 block is contiguous for cvt_all) ----
  char* ws = (char*)d_ws;
  size_t o = 0;
  int*      flag   = (int*)(ws + o);      o += 64;
  ushort_t* emb_b  = (ushort_t*)(ws + o); o += 12800000;  // 50000*128
  ushort_t* alocb  = (ushort_t*)(ws + o); o += 1024;      // 4*128
  ushort_t* gw1b   = (ushort_t*)(ws + o); o += 65536;     // 2*128*128
  ushort_t* gw2b   = (ushort_t*)(ws + o); o += 512;       // 2*128
  ushort_t* gw3b   = (ushort_t*)(ws + o); o += 131072;    // 2*256*128
  ushort_t* gbb    = (ushort_t*)(ws + o); o += 512;       // 2*128
  ushort_t* sessb  = (ushort_t*)(ws + o); o += 32768;     // 128*128
  ushort_t* hlb    = (ushort_t*)(ws + o); o += 1638400;   // 6400*128
  uint4*    w1f    = (uint4*)(ws + o);    o += 65536;     // 2 hops x 2048 uint4
  uint4*    w3f    = (uint4*)(ws + o);    o += 131072;    // 2 hops x 4096 uint4
  size_t fixed = o;
  int CHB = 16;
  if      (ws_size >= fixed + (size_t)128*173600) CHB = 128;
  else if (ws_size >= fixed + (size_t)64 *173600) CHB = 64;
  else if (ws_size >= fixed + (size_t)32 *173600) CHB = 32;
  ushort_t* out1c = (ushort_t*)(ws + o);  o += (size_t)CHB*153600;
  ushort_t* o0c   = (ushort_t*)(ws + o);  o += (size_t)CHB*12800;
  float*    score = (float*)(ws + o);

  float* outp = (float*)d_out;   // output is f32 storage

  // ---- dtype normalize + fragment pre-swizzle ----
  detect_kernel<<<1, 64, 0, stream>>>((const uint32_t*)d_in[6], flag);
  cvt_all<<<(6499328/4 + 255)/256, 256, 0, stream>>>(d_in[6], d_in[7], d_in[8], d_in[9],
                                                     d_in[10], d_in[11], emb_b, flag);
  prep_frags<<<48, 256, 0, stream>>>(gw1b, gw3b, w1f, w3f);

  sess_kernel<<<B_, 128, 0, stream>>>(item, mask_item, emb_b, sessb);
  local_mfma2<<<B_*4, 256, 0, stream>>>(inputs, adj, emb_b, alocb, hlb);

  int nchunk = B_ / CHB;
  for (int c = 0; c < nchunk; c++){
    int b0 = c * CHB;
    const int* fadj  = first_adj + (size_t)b0 * 600;
    const ushort_t* sbc = sessb + (size_t)b0 * D_;
    ushort_t*  hlc   = hlb  + (size_t)b0 * 50 * D_;
    float*     outc  = outp + (size_t)b0 * 50 * D_;
    int nA600 = CHB*600, nA50 = CHB*50, nTot = CHB*650;

    score_mfma_ab<<<(3*nA600)/128, 256, 0, stream>>>(sbc, emb_b, fadj, adj_all,
                                                     w1f, gw2b, score, nA600);
    out_mfma_ab<<<(nTot + 127)/128, 512, 0, stream>>>(score, inputs + b0*50, fadj, adj_all,
                                                      emb_b, w3f, gbb, o0c, out1c,
                                                      nA50, nTot, nA600);
    score_mfma_c<<<nA600/128, 256, 0, stream>>>(sbc, out1c, w1f + 2048, gw2b + 128, score);
    out_mfma_c<<<(nA50 + 127)/128, 512, 0, stream>>>(score, out1c, o0c,
                                                     w3f + 4096, gbb + 128,
                                                     hlc, outc, nA50);
  }
}

// Round 16
// 199.322 us; speedup vs baseline: 1.4308x; 1.0003x over previous
//
#include <hip/hip_runtime.h>
#include <stdint.h>

typedef unsigned short ushort_t;
typedef __attribute__((ext_vector_type(8))) short bf16x8;   // 4 VGPRs, 8 bf16
typedef __attribute__((ext_vector_type(4))) float f32x4;    // MFMA C/D

#define B_   128
#define S_   50
#define D_   128
#define ALPHA_ 0.2f

__device__ __forceinline__ float bf2f(ushort_t u){
  return __uint_as_float(((uint32_t)u) << 16);
}
__device__ __forceinline__ ushort_t f2bf(float f){
  uint32_t x = __float_as_uint(f);
  x = (x + 0x7fffu + ((x >> 16) & 1u)) >> 16;
  return (ushort_t)x;
}
__device__ __forceinline__ float leaky(float x){ return x >= 0.f ? x : ALPHA_*x; }

// per-block dtype detect: bf16-packed (1) vs f32 (0), from emb's first 64 words
__device__ __forceinline__ int detect_flag_block(const uint32_t* __restrict__ emb_raw){
  __shared__ int flg;
  if (threadIdx.x == 0){
    int ok = 1;
    for (int i = 0; i < 64; i++){
      uint32_t lo = emb_raw[i] & 0xffffu;
      uint32_t ex = (lo >> 7) & 0xFFu;
      if (!(lo == 0u || (ex >= 64u && ex <= 126u))) ok = 0;
    }
    flg = ok;
  }
  __syncthreads();
  return flg;
}

// ---- cvt_all: all six float tensors -> contiguous bf16 dst ----------------
__global__ void cvt_all(const void* __restrict__ p0, const void* __restrict__ p1,
                        const void* __restrict__ p2, const void* __restrict__ p3,
                        const void* __restrict__ p4, const void* __restrict__ p5,
                        ushort_t* __restrict__ dst){
  int flag = detect_flag_block((const uint32_t*)p0);
  const int seg_end[6] = {6400000, 6400512, 6433280, 6433536, 6499072, 6499328};
  int base = (blockIdx.x*256 + threadIdx.x) * 4;
  if (base >= 6499328) return;
  int s = 0;
  while (base >= seg_end[s]) s++;
  int segbase = (s == 0) ? 0 : seg_end[s-1];
  const void* src = (s==0)?p0:(s==1)?p1:(s==2)?p2:(s==3)?p3:(s==4)?p4:p5;
  int off = base - segbase;
  union { ushort_t u[4]; uint2 d2; } o;
  if (flag){
    o.d2 = *(const uint2*)((const ushort_t*)src + off);
  } else {
    float4 v = *(const float4*)((const float*)src + off);
    o.u[0] = f2bf(v.x); o.u[1] = f2bf(v.y); o.u[2] = f2bf(v.z); o.u[3] = f2bf(v.w);
  }
  *(uint2*)(dst + base) = o.d2;
}

// ---- prep_frags: RAW w1/w3 (+flag) -> pre-swizzled MFMA fragment buffers --
__global__ void prep_frags(const void* __restrict__ emb_raw,
                           const void* __restrict__ w1r, const void* __restrict__ w3r,
                           uint4* __restrict__ w1f, uint4* __restrict__ w3f){
  int flag = detect_flag_block((const uint32_t*)emb_raw);
  int id = blockIdx.x*256 + threadIdx.x;   // total 12288
  if (id >= 12288) return;
  if (id < 4096){
    int h = id >> 11, i = id & 2047;
    int kt = i >> 9, rem = i & 511, t = rem >> 6, ln = rem & 63;
    int q = ln >> 4, c = ln & 15;
    union { ushort_t u[8]; uint4 q4; } e;
    #pragma unroll
    for (int j = 0; j < 8; j++){
      int idx = h*16384 + (32*kt + q*8 + j)*128 + 16*t + c;
      e.u[j] = flag ? ((const ushort_t*)w1r)[idx] : f2bf(((const float*)w1r)[idx]);
    }
    w1f[h*2048 + i] = e.q4;
  } else {
    int id2 = id - 4096;
    int h = id2 >> 12, i = id2 & 4095;
    int kt = i >> 9, rem = i & 511, t = rem >> 6, ln = rem & 63;
    int q = ln >> 4, c = ln & 15;
    union { ushort_t u[8]; uint4 q4; } e;
    #pragma unroll
    for (int j = 0; j < 8; j++){
      int idx = h*32768 + (32*kt + q*8 + j)*128 + 16*t + c;
      e.u[j] = flag ? ((const ushort_t*)w3r)[idx] : f2bf(((const float*)w3r)[idx]);
    }
    w3f[h*4096 + i] = e.q4;
  }
}

// ---- merged sess + local attention ----------------------------------------
// blocks [0,512): local (b=blk>>2, i-tile mi=blk&3); blocks [512,576): sess
__global__ __launch_bounds__(256) void sess_local(
    const int* __restrict__ inputs, const int* __restrict__ adj,
    const int* __restrict__ item, const int* __restrict__ mask,
    const ushort_t* __restrict__ emb, const ushort_t* __restrict__ alocb,
    ushort_t* __restrict__ sessb, ushort_t* __restrict__ hlb){
  int blk = blockIdx.x;
  int tid = threadIdx.x;
  if (blk >= 512){
    // ---- sess: 2 b per block; b = (blk-512)*2 + tid/128, d = tid&127 ----
    int b = (blk - 512)*2 + (tid >> 7);
    int d = tid & 127;
    float acc = 0.f, den = 0.f;
    for (int s = 0; s < S_; s++){
      float fm = (float)mask[b*S_ + s];
      int id = item[b*S_ + s];
      acc += fm * bf2f(emb[(size_t)id*D_ + d]);
      den += fm;
    }
    sessb[b*D_ + d] = f2bf(acc / den);
    return;
  }
  // ---- local attention (identical to round-15 local_mfma2) ----
  __shared__ ushort_t hS[64][136];   // h[j][d], row stride 272B
  __shared__ float    attS[16][68];  // att tile
  __shared__ int      sids[64];
  int b  = blk >> 2;
  int mi = blk & 3;                  // i-tile: rows mi*16 .. mi*16+15
  if (tid < 64) sids[tid] = (tid < S_) ? inputs[b*S_ + tid] : 0;
  __syncthreads();
  for (int idx = tid; idx < 64*16; idx += 256){
    int j = idx >> 4, ch = idx & 15;
    uint4 v = {0u, 0u, 0u, 0u};
    if (j < S_) v = *(const uint4*)(emb + (size_t)sids[j]*D_ + ch*8);
    *(uint4*)(&hS[j][ch*8]) = v;
  }
  for (int idx = tid; idx < 16*64; idx += 256)
    attS[idx >> 6][idx & 63] = -9.0e15f;
  __syncthreads();

  int lane = tid & 63, wv = tid >> 6;       // wv = k
  int q = lane >> 4, c = lane & 15;

  f32x4 Eacc[4];
  #pragma unroll
  for (int ni = 0; ni < 4; ni++) Eacc[ni] = (f32x4){0.f,0.f,0.f,0.f};
  #pragma unroll
  for (int kt = 0; kt < 4; kt++){
    uint4 av = *(const uint4*)(alocb + wv*D_ + kt*32 + q*8);
    const uint32_t* ap = (const uint32_t*)&av;
    uint4 hv = *(const uint4*)(&hS[mi*16 + c][kt*32 + q*8]);
    const uint32_t* hp = (const uint32_t*)&hv;
    union { ushort_t u[8]; bf16x8 v; } afr;
    #pragma unroll
    for (int p = 0; p < 4; p++){
      float x0 = __uint_as_float(hp[p] << 16)         * __uint_as_float(ap[p] << 16);
      float x1 = __uint_as_float(hp[p] & 0xffff0000u) * __uint_as_float(ap[p] & 0xffff0000u);
      afr.u[2*p]   = f2bf(x0);
      afr.u[2*p+1] = f2bf(x1);
    }
    #pragma unroll
    for (int ni = 0; ni < 4; ni++){
      union { uint4 q4; bf16x8 v; } bfr;
      bfr.q4 = *(const uint4*)(&hS[ni*16 + c][kt*32 + q*8]);
      Eacc[ni] = __builtin_amdgcn_mfma_f32_16x16x32_bf16(afr.v, bfr.v, Eacc[ni], 0,0,0);
    }
  }
  const int* adjb = adj + (size_t)b*S_*S_;
  #pragma unroll
  for (int ni = 0; ni < 4; ni++){
    int j = ni*16 + c;
    #pragma unroll
    for (int r = 0; r < 4; r++){
      int i = mi*16 + q*4 + r;
      if (i < S_ && j < S_){
        int kk = adjb[i*S_ + j];
        if (kk == wv + 1) attS[q*4 + r][j] = leaky(Eacc[ni][r]);
      }
    }
  }
  __syncthreads();
  if (tid < 16){
    int i = mi*16 + tid;
    if (i < S_){
      float mx = -__builtin_inff();
      for (int j = 0; j < S_; j++) mx = fmaxf(mx, attS[tid][j]);
      float s = 0.f;
      for (int j = 0; j < S_; j++){ float e = __expf(attS[tid][j] - mx); attS[tid][j] = e; s += e; }
      float inv = 1.f / s;
      for (int j = 0; j < S_; j++) attS[tid][j] *= inv;
      for (int j = S_; j < 64; j++) attS[tid][j] = 0.f;
    } else {
      for (int j = 0; j < 64; j++) attS[tid][j] = 0.f;
    }
  }
  __syncthreads();
  f32x4 Pacc[2];
  Pacc[0] = (f32x4){0.f,0.f,0.f,0.f};
  Pacc[1] = (f32x4){0.f,0.f,0.f,0.f};
  #pragma unroll
  for (int kt = 0; kt < 2; kt++){
    union { ushort_t u[8]; bf16x8 v; } afr;
    const float* arow = &attS[c][kt*32 + q*8];
    #pragma unroll
    for (int j = 0; j < 8; j++) afr.u[j] = f2bf(arow[j]);
    #pragma unroll
    for (int nn = 0; nn < 2; nn++){
      int ni = 2*wv + nn;
      union { ushort_t u[8]; bf16x8 v; } bfr;
      #pragma unroll
      for (int jj = 0; jj < 8; jj++)
        bfr.u[jj] = hS[kt*32 + q*8 + jj][ni*16 + c];
      Pacc[nn] = __builtin_amdgcn_mfma_f32_16x16x32_bf16(afr.v, bfr.v, Pacc[nn], 0,0,0);
    }
  }
  #pragma unroll
  for (int nn = 0; nn < 2; nn++){
    int d = (2*wv + nn)*16 + c;
    #pragma unroll
    for (int r = 0; r < 4; r++){
      int i = mi*16 + q*4 + r;
      if (i < S_) hlb[((size_t)b*S_ + i)*D_ + d] = f2bf(Pacc[nn][r]);
    }
  }
}

// ---- merged score A+B: rows [0,nA) A-mode, [nA,3nA) B-mode ----------------
__global__ __launch_bounds__(256) void score_mfma_ab(
    const ushort_t* __restrict__ sessb, const ushort_t* __restrict__ emb,
    const int* __restrict__ neigh1, const int* __restrict__ adj_all,
    const uint4* __restrict__ w1f, const ushort_t* __restrict__ w2,
    float* __restrict__ score, int nA){
  __shared__ uint4 bfrag[2048];      // 32 KB, coalesced copy from w1f
  int tid = threadIdx.x;
  for (int i = tid; i < 2048; i += 256) bfrag[i] = w1f[i];
  __syncthreads();
  int lane = tid & 63, wave = tid >> 6;
  int m = lane & 15, q = lane >> 4;
  float w2v[8];
  #pragma unroll
  for (int t = 0; t < 8; t++) w2v[t] = bf2f(w2[16*t + m]);

  for (int it = 0; it < 2; it++){
    int row_base = blockIdx.x*128 + it*64 + wave*16;
    int row = row_base + m;
    const ushort_t* nrow; int b;
    if (row < nA){
      nrow = emb + (size_t)neigh1[row]*D_;
      b = row / 600;
    } else {
      int r2 = row - nA;
      nrow = emb + (size_t)adj_all[(size_t)neigh1[r2>>1]*2 + (r2&1)]*D_;
      b = r2 / 1200;
    }
    const ushort_t* srow = sessb + (size_t)b*D_;

    f32x4 acc[8];
    #pragma unroll
    for (int t = 0; t < 8; t++) acc[t] = (f32x4){0.f,0.f,0.f,0.f};
    #pragma unroll
    for (int kt = 0; kt < 4; kt++){
      uint4 nv = *(const uint4*)(nrow + kt*32 + q*8);
      uint4 sv = *(const uint4*)(srow + kt*32 + q*8);
      const uint32_t* np = (const uint32_t*)&nv;
      const uint32_t* sp = (const uint32_t*)&sv;
      union { ushort_t u[8]; bf16x8 v; } afr;
      #pragma unroll
      for (int p = 0; p < 4; p++){
        uint32_t n2 = np[p], s2 = sp[p];
        float a0 = __uint_as_float(n2 << 16)          * __uint_as_float(s2 << 16);
        float a1 = __uint_as_float(n2 & 0xffff0000u)  * __uint_as_float(s2 & 0xffff0000u);
        afr.u[2*p]   = f2bf(a0);
        afr.u[2*p+1] = f2bf(a1);
      }
      #pragma unroll
      for (int t = 0; t < 8; t++){
        union { uint4 q4; bf16x8 v; } bfr;
        bfr.q4 = bfrag[(kt*8 + t)*64 + lane];
        acc[t] = __builtin_amdgcn_mfma_f32_16x16x32_bf16(afr.v, bfr.v, acc[t], 0, 0, 0);
      }
    }
    #pragma unroll
    for (int r = 0; r < 4; r++){
      float s = 0.f;
      #pragma unroll
      for (int t = 0; t < 8; t++) s += leaky(acc[t][r]) * w2v[t];
      s += __shfl_xor(s, 1, 64);
      s += __shfl_xor(s, 2, 64);
      s += __shfl_xor(s, 4, 64);
      s += __shfl_xor(s, 8, 64);
      if (m == 0) score[row_base + q*4 + r] = s;
    }
  }
}

// ---- score C: neigh = out1[row] -------------------------------------------
__global__ __launch_bounds__(256) void score_mfma_c(
    const ushort_t* __restrict__ sessb, const ushort_t* __restrict__ out1,
    const uint4* __restrict__ w1f, const ushort_t* __restrict__ w2,
    float* __restrict__ score){
  __shared__ uint4 bfrag[2048];
  int tid = threadIdx.x;
  for (int i = tid; i < 2048; i += 256) bfrag[i] = w1f[i];
  __syncthreads();
  int lane = tid & 63, wave = tid >> 6;
  int m = lane & 15, q = lane >> 4;
  float w2v[8];
  #pragma unroll
  for (int t = 0; t < 8; t++) w2v[t] = bf2f(w2[16*t + m]);
  for (int it = 0; it < 2; it++){
    int row_base = blockIdx.x*128 + it*64 + wave*16;
    int row = row_base + m;
    const ushort_t* nrow = out1 + (size_t)row*D_;
    int b = row / 600;
    const ushort_t* srow = sessb + (size_t)b*D_;
    f32x4 acc[8];
    #pragma unroll
    for (int t = 0; t < 8; t++) acc[t] = (f32x4){0.f,0.f,0.f,0.f};
    #pragma unroll
    for (int kt = 0; kt < 4; kt++){
      uint4 nv = *(const uint4*)(nrow + kt*32 + q*8);
      uint4 sv = *(const uint4*)(srow + kt*32 + q*8);
      const uint32_t* np = (const uint32_t*)&nv;
      const uint32_t* sp = (const uint32_t*)&sv;
      union { ushort_t u[8]; bf16x8 v; } afr;
      #pragma unroll
      for (int p = 0; p < 4; p++){
        uint32_t n2 = np[p], s2 = sp[p];
        float a0 = __uint_as_float(n2 << 16)          * __uint_as_float(s2 << 16);
        float a1 = __uint_as_float(n2 & 0xffff0000u)  * __uint_as_float(s2 & 0xffff0000u);
        afr.u[2*p]   = f2bf(a0);
        afr.u[2*p+1] = f2bf(a1);
      }
      #pragma unroll
      for (int t = 0; t < 8; t++){
        union { uint4 q4; bf16x8 v; } bfr;
        bfr.q4 = bfrag[(kt*8 + t)*64 + lane];
        acc[t] = __builtin_amdgcn_mfma_f32_16x16x32_bf16(afr.v, bfr.v, acc[t], 0, 0, 0);
      }
    }
    #pragma unroll
    for (int r = 0; r < 4; r++){
      float s = 0.f;
      #pragma unroll
      for (int t = 0; t < 8; t++) s += leaky(acc[t][r]) * w2v[t];
      s += __shfl_xor(s, 1, 64);
      s += __shfl_xor(s, 2, 64);
      s += __shfl_xor(s, 4, 64);
      s += __shfl_xor(s, 8, 64);
      if (m == 0) score[row_base + q*4 + r] = s;
    }
  }
}

// ---- shared out helpers ---------------------------------------------------
template<int K>
__device__ __forceinline__ void softmaxK(const float* __restrict__ sc, float att[K]){
  float mx = -__builtin_inff();
  #pragma unroll
  for (int k = 0; k < K; k++){ att[k] = sc[k]; mx = fmaxf(mx, att[k]); }
  float s = 0.f;
  #pragma unroll
  for (int k = 0; k < K; k++){ att[k] = __expf(att[k] - mx); s += att[k]; }
  float inv = 1.f / s;
  #pragma unroll
  for (int k = 0; k < K; k++) att[k] *= inv;
}

template<int K>
__device__ __forceinline__ void out_tile(
    int lane, const uint4* __restrict__ afrag,
    const ushort_t* __restrict__ sptr, const ushort_t* const nptr[K],
    const float att[K], f32x4 acc[8]){
  int q = lane >> 4;
  #pragma unroll
  for (int kt = 0; kt < 8; kt++){
    union { ushort_t u[8]; uint4 q4; bf16x8 v; } bfr;
    if (kt < 4){
      bfr.q4 = *(const uint4*)(sptr + kt*32 + q*8);
    } else {
      float g[8] = {0,0,0,0,0,0,0,0};
      #pragma unroll
      for (int k = 0; k < K; k++){
        uint4 nv = *(const uint4*)(nptr[k] + (kt-4)*32 + q*8);
        const uint32_t* np = (const uint32_t*)&nv;
        #pragma unroll
        for (int p = 0; p < 4; p++){
          g[2*p]   = fmaf(att[k], __uint_as_float(np[p] << 16),         g[2*p]);
          g[2*p+1] = fmaf(att[k], __uint_as_float(np[p] & 0xffff0000u), g[2*p+1]);
        }
      }
      #pragma unroll
      for (int j = 0; j < 8; j++) bfr.u[j] = f2bf(g[j]);
    }
    #pragma unroll
    for (int t = 0; t < 8; t++){
      union { uint4 q4; bf16x8 v; } af;
      af.q4 = afrag[(kt*8 + t)*64 + lane];
      acc[t] = __builtin_amdgcn_mfma_f32_16x16x32_bf16(af.v, bfr.v, acc[t], 0, 0, 0);
    }
  }
}

// ---- merged out A+B: 512 threads (8 waves share 64 KB w3 LDS), 128 rows/blk
__global__ __launch_bounds__(512) void out_mfma_ab(
    const float* __restrict__ score, const int* __restrict__ idx,
    const int* __restrict__ nbr, const int* __restrict__ adj_all,
    const ushort_t* __restrict__ emb, const uint4* __restrict__ w3f,
    const ushort_t* __restrict__ bias,
    ushort_t* __restrict__ o0c, ushort_t* __restrict__ out1c,
    int nA, int nTot, int scoreBbase){
  __shared__ uint4 afrag[4096];   // 64 KB, coalesced copy from w3f
  int tid = threadIdx.x;
  for (int i = tid; i < 4096; i += 512) afrag[i] = w3f[i];
  __syncthreads();
  int lane = tid & 63, wave = tid >> 6;   // 8 waves
  int mrow = lane & 15, q = lane >> 4;
  float bv[8][4];
  #pragma unroll
  for (int t = 0; t < 8; t++){
    const ushort_t* bp = bias + 16*t + q*4;
    #pragma unroll
    for (int r = 0; r < 4; r++) bv[t][r] = bf2f(bp[r]);
  }
  int row_base = blockIdx.x*128 + wave*16;
  int row = row_base + mrow;
  bool active = row < nTot;
  int rowc = active ? row : (nTot - 1);
  bool isA = rowc < nA;
  f32x4 acc[8];
  #pragma unroll
  for (int t = 0; t < 8; t++) acc[t] = (f32x4){0.f,0.f,0.f,0.f};
  if (isA){
    const ushort_t* sptr = emb + (size_t)idx[rowc]*D_;
    const ushort_t* nptr[12];
    #pragma unroll
    for (int k = 0; k < 12; k++) nptr[k] = emb + (size_t)nbr[rowc*12 + k]*D_;
    float att[12];
    softmaxK<12>(score + (size_t)rowc*12, att);
    out_tile<12>(lane, afrag, sptr, nptr, att, acc);
  } else {
    int rB = rowc - nA;
    const ushort_t* sptr = emb + (size_t)nbr[rB]*D_;
    const ushort_t* nptr[2];
    #pragma unroll
    for (int k = 0; k < 2; k++) nptr[k] = emb + (size_t)adj_all[(size_t)nbr[rB]*2 + k]*D_;
    float att[2];
    softmaxK<2>(score + scoreBbase + (size_t)rB*2, att);
    out_tile<2>(lane, afrag, sptr, nptr, att, acc);
  }
  if (active){
    ushort_t* dst = isA ? (o0c + (size_t)row*D_) : (out1c + (size_t)(row - nA)*D_);
    #pragma unroll
    for (int t = 0; t < 8; t++){
      int col0 = 16*t + q*4;
      union { ushort_t u[4]; uint2 d2; } pk;
      #pragma unroll
      for (int r = 0; r < 4; r++) pk.u[r] = f2bf(fmaxf(acc[t][r] + bv[t][r], 0.f));
      *(uint2*)(dst + col0) = pk.d2;
    }
  }
}

// ---- out C: 512 threads, self=o0c[row], neigh=out1[row*12+k], f32 out -----
__global__ __launch_bounds__(512) void out_mfma_c(
    const float* __restrict__ score, const ushort_t* __restrict__ out1,
    const ushort_t* __restrict__ selfsrc, const uint4* __restrict__ w3f,
    const ushort_t* __restrict__ bias,
    const ushort_t* __restrict__ addsrc, float* __restrict__ outf, int nrows){
  __shared__ uint4 afrag[4096];
  int tid = threadIdx.x;
  for (int i = tid; i < 4096; i += 512) afrag[i] = w3f[i];
  __syncthreads();
  int lane = tid & 63, wave = tid >> 6;
  int mrow = lane & 15, q = lane >> 4;
  float bv[8][4];
  #pragma unroll
  for (int t = 0; t < 8; t++){
    const ushort_t* bp = bias + 16*t + q*4;
    #pragma unroll
    for (int r = 0; r < 4; r++) bv[t][r] = bf2f(bp[r]);
  }
  int row_base = blockIdx.x*128 + wave*16;
  int row = row_base + mrow;
  bool active = row < nrows;
  int rowc = active ? row : (nrows - 1);
  const ushort_t* sptr = selfsrc + (size_t)rowc*D_;
  const ushort_t* nptr[12];
  #pragma unroll
  for (int k = 0; k < 12; k++) nptr[k] = out1 + (size_t)(rowc*12 + k)*D_;
  float att[12];
  softmaxK<12>(score + (size_t)rowc*12, att);
  f32x4 acc[8];
  #pragma unroll
  for (int t = 0; t < 8; t++) acc[t] = (f32x4){0.f,0.f,0.f,0.f};
  out_tile<12>(lane, afrag, sptr, nptr, att, acc);
  if (active){
    #pragma unroll
    for (int t = 0; t < 8; t++){
      int col0 = 16*t + q*4;
      float v[4];
      const ushort_t* ap = addsrc + (size_t)row*D_ + col0;
      #pragma unroll
      for (int r = 0; r < 4; r++)
        v[r] = fmaxf(acc[t][r] + bv[t][r], 0.f) + bf2f(ap[r]);
      *(f32x4*)(outf + (size_t)row*D_ + col0) = (f32x4){v[0], v[1], v[2], v[3]};
    }
  }
}

extern "C" void kernel_launch(void* const* d_in, const int* in_sizes, int n_in,
                              void* d_out, int out_size, void* d_ws, size_t ws_size,
                              hipStream_t stream) {
  const int* inputs    = (const int*)d_in[0];
  const int* adj       = (const int*)d_in[1];
  const int* mask_item = (const int*)d_in[2];
  const int* item      = (const int*)d_in[3];
  const int* first_adj = (const int*)d_in[4];    // neigh1 (B,600)
  const int* adj_all   = (const int*)d_in[5];    // (50000,2)

  // ---- ws layout (bf16 block is contiguous for cvt_all) ----
  char* ws = (char*)d_ws;
  size_t o = 0;
  ushort_t* emb_b  = (ushort_t*)(ws + o); o += 12800000;  // 50000*128
  ushort_t* alocb  = (ushort_t*)(ws + o); o += 1024;      // 4*128
  ushort_t* gw1b   = (ushort_t*)(ws + o); o += 65536;     // 2*128*128 (dead; kept for cvt segments)
  ushort_t* gw2b   = (ushort_t*)(ws + o); o += 512;       // 2*128
  ushort_t* gw3b   = (ushort_t*)(ws + o); o += 131072;    // 2*256*128 (dead)
  ushort_t* gbb    = (ushort_t*)(ws + o); o += 512;       // 2*128
  ushort_t* sessb  = (ushort_t*)(ws + o); o += 32768;     // 128*128
  ushort_t* hlb    = (ushort_t*)(ws + o); o += 1638400;   // 6400*128
  uint4*    w1f    = (uint4*)(ws + o);    o += 65536;     // 2 hops x 2048 uint4
  uint4*    w3f    = (uint4*)(ws + o);    o += 131072;    // 2 hops x 4096 uint4
  size_t fixed = o;
  (void)gw1b; (void)gw3b;
  int CHB = 16;
  if      (ws_size >= fixed + (size_t)128*173600) CHB = 128;
  else if (ws_size >= fixed + (size_t)64 *173600) CHB = 64;
  else if (ws_size >= fixed + (size_t)32 *173600) CHB = 32;
  ushort_t* out1c = (ushort_t*)(ws + o);  o += (size_t)CHB*153600;
  ushort_t* o0c   = (ushort_t*)(ws + o);  o += (size_t)CHB*12800;
  float*    score = (float*)(ws + o);

  float* outp = (float*)d_out;   // output is f32 storage

  // ---- dtype normalize + fragment pre-swizzle (2 launches, self-detecting)
  cvt_all<<<(6499328/4 + 255)/256, 256, 0, stream>>>(d_in[6], d_in[7], d_in[8], d_in[9],
                                                     d_in[10], d_in[11], emb_b);
  prep_frags<<<48, 256, 0, stream>>>(d_in[6], d_in[8], d_in[10], w1f, w3f);

  // ---- merged sess + local ----
  sess_local<<<576, 256, 0, stream>>>(inputs, adj, item, mask_item,
                                      emb_b, alocb, sessb, hlb);

  int nchunk = B_ / CHB;
  for (int c = 0; c < nchunk; c++){
    int b0 = c * CHB;
    const int* fadj  = first_adj + (size_t)b0 * 600;
    const ushort_t* sbc = sessb + (size_t)b0 * D_;
    ushort_t*  hlc   = hlb  + (size_t)b0 * 50 * D_;
    float*     outc  = outp + (size_t)b0 * 50 * D_;
    int nA600 = CHB*600, nA50 = CHB*50, nTot = CHB*650;

    score_mfma_ab<<<(3*nA600)/128, 256, 0, stream>>>(sbc, emb_b, fadj, adj_all,
                                                     w1f, gw2b, score, nA600);
    out_mfma_ab<<<(nTot + 127)/128, 512, 0, stream>>>(score, inputs + b0*50, fadj, adj_all,
                                                      emb_b, w3f, gbb, o0c, out1c,
                                                      nA50, nTot, nA600);
    score_mfma_c<<<nA600/128, 256, 0, stream>>>(sbc, out1c, w1f + 2048, gw2b + 128, score);
    out_mfma_c<<<(nA50 + 127)/128, 512, 0, stream>>>(score, out1c, o0c,
                                                     w3f + 4096, gbb + 128,
                                                     hlc, outc, nA50);
  }
}